// Round 11
// baseline (256.157 us; speedup 1.0000x reference)
//
#include <hip/hip_runtime.h>
#include <hip/hip_bf16.h>
#include <hip/hip_fp16.h>
#include <math.h>

#define BATCH 64
#define LAT   256
#define DVOX  64
#define VOX   (DVOX*DVOX*DVOX)   // 262144

typedef __attribute__((ext_vector_type(8))) short short8;
typedef __attribute__((ext_vector_type(4))) float f32x4;
typedef unsigned uint32x4 __attribute__((ext_vector_type(4), aligned(4)));  // 4B-aligned vec load

// ---------------- kernel 0: enc -> bf16, build rotation matrices -----------
__global__ void prep_kernel(const float* __restrict__ enc,      // [64,256]
                            const float* __restrict__ angles,   // [64,3]
                            unsigned short* __restrict__ encB,  // [64,256] bf16 bits
                            float* __restrict__ Rmat) {         // [64,9]
    int tid = threadIdx.x;
    for (int idx = tid; idx < BATCH * LAT; idx += blockDim.x) {
        __hip_bfloat16 h = __float2bfloat16(enc[idx]);
        encB[idx] = *reinterpret_cast<unsigned short*>(&h);
    }
    if (tid < BATCH) {
        float ax = angles[tid*3+0], ay = angles[tid*3+1], az = angles[tid*3+2];
        float cx = cosf(ax), sx = sinf(ax);
        float cy = cosf(ay), sy = sinf(ay);
        float cz = cosf(az), sz = sinf(az);
        float* R = Rmat + tid * 9;
        R[0] = cz*cy;  R[1] = cz*sy*sx - sz*cx;  R[2] = cz*sy*cx + sz*sx;
        R[3] = sz*cy;  R[4] = sz*sy*sx + cz*cx;  R[5] = sz*sy*cx - cz*sx;
        R[6] = -sy;    R[7] = cy*sx;             R[8] = cy*cx;
    }
}

// ---------------- kernel 1: MFMA GEMM + sigmoid^8 -> fp16 voxels -----------
// (byte-identical to round 10 — held fixed for attribution)
__global__ __launch_bounds__(256, 2) void gemm_mfma_kernel(
        const unsigned short* __restrict__ encB,  // [64,256] bf16
        const float* __restrict__ W,              // [256, 262144]
        const float* __restrict__ bias,           // [262144]
        __half* __restrict__ vox) {               // [64, 262144] fp16
    int wave = threadIdx.x >> 6;
    int lane = threadIdx.x & 63;
    int l15 = lane & 15, l4 = lane >> 4;
    int n4 = blockIdx.x * 256 + wave * 64 + 4 * l15;  // cols n4..n4+3

    f32x4 acc[4][4];   // [tile][mt]
#pragma unroll
    for (int t = 0; t < 4; ++t)
#pragma unroll
        for (int mt = 0; mt < 4; ++mt) acc[t][mt] = (f32x4){0.f, 0.f, 0.f, 0.f};

    const unsigned short* ap = encB + l15 * LAT + l4 * 8;
    const float* wp = W + (size_t)(l4 * 8) * VOX + n4;

    float4 wA[8], wB[8];
#pragma unroll
    for (int j = 0; j < 8; ++j)
        wA[j] = *(const float4*)(wp + (size_t)j * VOX);

    auto consume = [&](const float4* w, int kb) {
        short8 a[4];
#pragma unroll
        for (int mt = 0; mt < 4; ++mt)
            a[mt] = *(const short8*)(ap + mt * 16 * LAT + kb);
        short8 bf[4];
#pragma unroll
        for (int t = 0; t < 4; ++t) {
            unsigned bw[4];
#pragma unroll
            for (int dw = 0; dw < 4; ++dw) {
                unsigned u0 = __float_as_uint(((const float*)&w[2 * dw])[t])     + 0x8000u;
                unsigned u1 = __float_as_uint(((const float*)&w[2 * dw + 1])[t]) + 0x8000u;
                bw[dw] = __builtin_amdgcn_perm(u1, u0, 0x07060302u);  // hi16(u0)|hi16(u1)<<16
            }
            bf[t] = *reinterpret_cast<short8*>(bw);
        }
#pragma unroll
        for (int t = 0; t < 4; ++t)
#pragma unroll
            for (int mt = 0; mt < 4; ++mt)
                acc[t][mt] = __builtin_amdgcn_mfma_f32_16x16x32_bf16(a[mt], bf[t], acc[t][mt], 0, 0, 0);
    };

#pragma unroll
    for (int kb2 = 0; kb2 < LAT; kb2 += 64) {
        {   // prefetch odd buffer (kb2+32 always < LAT)
            const float* q = wp + (size_t)(kb2 + 32) * VOX;
#pragma unroll
            for (int j = 0; j < 8; ++j) wB[j] = *(const float4*)(q + (size_t)j * VOX);
        }
        consume(wA, kb2);
        if (kb2 + 64 < LAT) {
            const float* q = wp + (size_t)(kb2 + 64) * VOX;
#pragma unroll
            for (int j = 0; j < 8; ++j) wA[j] = *(const float4*)(q + (size_t)j * VOX);
        }
        consume(wB, kb2 + 32);
    }

    float4 bv = *(const float4*)(bias + n4);
#pragma unroll
    for (int mt = 0; mt < 4; ++mt) {
#pragma unroll
        for (int r = 0; r < 4; ++r) {
            int b = mt * 16 + l4 * 4 + r;
            float s[4];
#pragma unroll
            for (int t = 0; t < 4; ++t) {
                float x = acc[t][mt][r] + ((const float*)&bv)[t];
                float v = 1.f / (1.f + __expf(-x));   // sigmoid
                v = v * v; v = v * v; v = v * v;      // ^8
                s[t] = v;
            }
            __half2 h01 = __floats2half2_rn(s[0], s[1]);
            __half2 h23 = __floats2half2_rn(s[2], s[3]);
            uint2 pk;
            pk.x = *reinterpret_cast<unsigned*>(&h01);
            pk.y = *reinterpret_cast<unsigned*>(&h23);
            *reinterpret_cast<uint2*>(vox + (size_t)b * VOX + n4) = pk;
        }
    }
}

// ---------------- kernel 2: 4-wave cooperative LDS-brick resample ----------
// MEASUREMENT BUILD: the full per-pixel computation (staging + sampling +
// fold) is repeated REP=4 times inside the dispatch (idempotent; result of
// last rep written). dur(this dispatch) ≈ 4x render => render surfaces in
// top-5 with counters, and (total - 142)/3 = render time either way.
#define REP 4

__device__ __forceinline__ float zlerp(unsigned e, float fz) {
    __half2 h = *reinterpret_cast<__half2*>(&e);
    float2 f = __half22float2(h);
    return f.x + (f.y - f.x) * fz;
}

__global__ __launch_bounds__(256) void render_lds_kernel(
        const __half* __restrict__ vox,   // [64, 262144] fp16
        const float* __restrict__ Rmat,   // [64,9]
        float* __restrict__ out) {        // [64,1,64,64]
    __shared__ unsigned sV[16 * 16 * 17]; // 17408 B brick, row stride 17
    __shared__ float sT[4][64], sE[4][64];

    int bid  = blockIdx.x;
    int b    = bid & 63;                  // bid%8 == b%8 -> XCD affinity
    int tile = bid >> 6;
    int t    = threadIdx.x;
    int pix  = t & 63, seg = t >> 6;      // seg == wave id
    int i0 = (tile >> 3) * 8, j0 = (tile & 7) * 8;
    int i = i0 + (pix >> 3);
    int j = j0 + (pix & 7);

    const float* Rb = Rmat + b * 9;       // uniform -> scalar loads
    float R0 = Rb[0], R1 = Rb[1], R2 = Rb[2];
    float R3 = Rb[3], R4 = Rb[4], R5 = Rb[5];
    float R6 = Rb[6], R7 = Rb[7], R8 = Rb[8];

    const float c = (DVOX - 1) * 0.5f;    // 31.5
    float di = (float)i - c, dj = (float)j - c;
    float xb = fmaf(R0, di, fmaf(R1, dj, c));
    float yb = fmaf(R3, di, fmaf(R4, dj, c));
    float zb = fmaf(R6, di, fmaf(R7, dj, c));

    float dic = (float)i0 + 3.5f - c;     // tile-center offsets (uniform)
    float djc = (float)j0 + 3.5f - c;
    float hwx = 3.5f * (fabsf(R0) + fabsf(R1) + fabsf(R2)) + 1e-3f;
    float hwy = 3.5f * (fabsf(R3) + fabsf(R4) + fabsf(R5)) + 1e-3f;
    float hwz = 3.5f * (fabsf(R6) + fabsf(R7) + fabsf(R8)) + 1e-3f;

    const unsigned short* V = (const unsigned short*)vox + (size_t)b * VOX;

    // this thread's staging row: x = t>>4, y = t&15
    int rx = t >> 4, ry = t & 15;
    unsigned d[9];
    int xlo_n, ylo_n, zlo_n, s_n;

    auto bbox = [&](int ch) {
        float dkc = (float)(ch * 8) + 3.5f - c;
        float xc = fmaf(R0, dic, fmaf(R1, djc, fmaf(R2, dkc, c)));
        float yc = fmaf(R3, dic, fmaf(R4, djc, fmaf(R5, dkc, c)));
        float zc = fmaf(R6, dic, fmaf(R7, djc, fmaf(R8, dkc, c)));
        xlo_n = (int)floorf(xc - hwx);
        ylo_n = (int)floorf(yc - hwy);
        zlo_n = (int)floorf(zc - hwz);
        s_n   = zlo_n & ~1;
    };
    auto issue = [&]() {
        int gxc = min(max(xlo_n + rx, 0), DVOX - 1);
        int gyc = min(max(ylo_n + ry, 0), DVOX - 1);
        const unsigned* p = (const unsigned*)(V + ((gxc << 12) + (gyc << 6) + s_n));
        uint32x4 q0 = *(const uint32x4*)p;        // global_load_dwordx4 (4B-align ok)
        uint32x4 q1 = *(const uint32x4*)(p + 4);
        unsigned q2 = p[8];
        d[0] = q0[0]; d[1] = q0[1]; d[2] = q0[2]; d[3] = q0[3];
        d[4] = q1[0]; d[5] = q1[1]; d[6] = q1[2]; d[7] = q1[3];
        d[8] = q2;
    };

    float img_final = 0.f;
#pragma unroll 1
    for (int rep = 0; rep < REP; ++rep) {

        bbox(7); issue();
        int xlo = xlo_n, ylo = ylo_n, zlo = zlo_n, s = s_n;

        float img = 0.f;                  // live in wave 0 only
#pragma unroll 1
        for (int ch = 7; ch >= 0; --ch) { // back-to-front chunks of 8 z
            bool zint = (zlo >= 0) && (zlo + 17 <= DVOX);

            // ---- pack this thread's row into the brick --------------------
            {
                bool rv = ((unsigned)(xlo + rx) < (unsigned)DVOX) &
                          ((unsigned)(ylo + ry) < (unsigned)DVOX);
                unsigned tt[9];
#pragma unroll
                for (int k = 0; k < 9; ++k) tt[k] = d[k];
                if (!zint) {              // block-uniform branch
#pragma unroll
                    for (int k = 0; k < 9; ++k) {
                        int h0 = s + 2 * k;
                        unsigned m = (((unsigned)h0 < (unsigned)DVOX) ? 0x0000FFFFu : 0u)
                                   | (((unsigned)(h0 + 1) < (unsigned)DVOX) ? 0xFFFF0000u : 0u);
                        tt[k] &= m;
                    }
                }
                unsigned rvm = rv ? 0xFFFFFFFFu : 0u;
#pragma unroll
                for (int k = 0; k < 9; ++k) tt[k] &= rvm;

                unsigned A[8];
#pragma unroll
                for (int m = 0; m < 8; ++m)
                    A[m] = (tt[m] >> 16) | (tt[m + 1] << 16);   // v_alignbit

                unsigned* wrow = sV + t * 17;
                if (zlo & 1) {            // block-uniform
#pragma unroll
                    for (int m = 0; m < 8; ++m) {
                        wrow[2 * m]     = A[m];
                        wrow[2 * m + 1] = tt[m + 1];
                    }
                } else {
#pragma unroll
                    for (int m = 0; m < 8; ++m) {
                        wrow[2 * m]     = tt[m];
                        wrow[2 * m + 1] = A[m];
                    }
                }
            }
            __syncthreads();

            // ---- issue NEXT chunk's loads (hidden under sampling) ---------
            if (ch > 0) { bbox(ch - 1); issue(); }

            // ---- sample this wave's 2-z segment, back-to-front ------------
            float T = 1.f, E = 0.f;
            int k0 = ch * 8;
#pragma unroll
            for (int q = 1; q >= 0; --q) {    // kk = 2*seg+1, then 2*seg
                int kk = 2 * seg + q;
                float dk = (float)(k0 + kk) - c;
                float x = fmaf(R2, dk, xb);
                float y = fmaf(R5, dk, yb);
                float z = fmaf(R8, dk, zb);

                float xf = floorf(x), yf = floorf(y), zf = floorf(z);
                float fx = x - xf, fy = y - yf, fz = z - zf;
                int xi = (int)xf - xlo;   // [0,14]
                int yi = (int)yf - ylo;
                int zi = (int)zf - zlo;
                const unsigned* e = sV + (xi * 272 + yi * 17 + zi);

                float c00 = zlerp(e[0],   fz);   // (x0,y0)
                float c01 = zlerp(e[17],  fz);   // (x0,y1)
                float c10 = zlerp(e[272], fz);   // (x1,y0)
                float c11 = zlerp(e[289], fz);   // (x1,y1)
                float c0 = c00 + (c01 - c00) * fy;
                float c1 = c10 + (c11 - c10) * fy;
                float a  = c0  + (c1  - c0 ) * fx;

                E = E * (1.f - a) + a;
                T *= (1.f - a);
            }
            sT[seg][pix] = T;
            sE[seg][pix] = E;
            __syncthreads();

            // ---- wave 0 folds the 4 segments (back seg 3 first) -----------
            if (seg == 0) {
                float im = img;
#pragma unroll
                for (int ss = 3; ss >= 0; --ss)
                    im = fmaf(sT[ss][pix], im, sE[ss][pix]);
                img = im;
            }

            xlo = xlo_n; ylo = ylo_n; zlo = zlo_n; s = s_n;
        }

        asm volatile("" : "+v"(img));     // keep each rep live (no DCE/CSE)
        img_final = img;
    }

    if (seg == 0)
        out[b * (DVOX * DVOX) + i * DVOX + j] = 2.f * img_final - 1.f;
}

// ---------------------------------------------------------------------------
extern "C" void kernel_launch(void* const* d_in, const int* in_sizes, int n_in,
                              void* d_out, int out_size, void* d_ws, size_t ws_size,
                              hipStream_t stream) {
    const float* enc    = (const float*)d_in[0];
    const float* W      = (const float*)d_in[1];
    const float* bias   = (const float*)d_in[2];
    const float* angles = (const float*)d_in[3];
    float* out = (float*)d_out;

    char* ws = (char*)d_ws;
    unsigned short* encB = (unsigned short*)ws;           // 32 KB
    float* Rmat          = (float*)(ws + 32768);          // 2.3 KB
    __half* vox          = (__half*)(ws + 65536);         // 32 MiB

    prep_kernel<<<1, 256, 0, stream>>>(enc, angles, encB, Rmat);
    gemm_mfma_kernel<<<VOX / 256, 256, 0, stream>>>(encB, W, bias, vox);
    render_lds_kernel<<<BATCH * 64, 256, 0, stream>>>(vox, Rmat, out);
}

// Round 12
// 141.824 us; speedup vs baseline: 1.8062x; 1.8062x over previous
//
#include <hip/hip_runtime.h>
#include <hip/hip_bf16.h>
#include <hip/hip_fp16.h>
#include <math.h>

#define BATCH 64
#define LAT   256
#define DVOX  64
#define VOX   (DVOX*DVOX*DVOX)   // 262144

typedef __attribute__((ext_vector_type(8))) short short8;
typedef __attribute__((ext_vector_type(4))) float f32x4;
typedef unsigned uint32x4 __attribute__((ext_vector_type(4), aligned(4)));  // 4B-aligned vec load

// ---------------- kernel 0: enc -> bf16, build rotation matrices -----------
__global__ void prep_kernel(const float* __restrict__ enc,      // [64,256]
                            const float* __restrict__ angles,   // [64,3]
                            unsigned short* __restrict__ encB,  // [64,256] bf16 bits
                            float* __restrict__ Rmat) {         // [64,9]
    int tid = threadIdx.x;
    for (int idx = tid; idx < BATCH * LAT; idx += blockDim.x) {
        __hip_bfloat16 h = __float2bfloat16(enc[idx]);
        encB[idx] = *reinterpret_cast<unsigned short*>(&h);
    }
    if (tid < BATCH) {
        float ax = angles[tid*3+0], ay = angles[tid*3+1], az = angles[tid*3+2];
        float cx = cosf(ax), sx = sinf(ax);
        float cy = cosf(ay), sy = sinf(ay);
        float cz = cosf(az), sz = sinf(az);
        float* R = Rmat + tid * 9;
        R[0] = cz*cy;  R[1] = cz*sy*sx - sz*cx;  R[2] = cz*sy*cx + sz*sx;
        R[3] = sz*cy;  R[4] = sz*sy*sx + cz*cx;  R[5] = sz*sy*cx - cz*sx;
        R[6] = -sy;    R[7] = cy*sx;             R[8] = cy*cx;
    }
}

// ---------------- kernel 1: MFMA GEMM + sigmoid^8 -> fp16 voxels -----------
// R10 shape (4 interleaved 16-col tiles, float4 W loads) + 3-DEEP register
// pipeline: buffers w0/w1/w2 rotate so TWO k-blocks (4KB/wave) are always in
// flight — GEMM measured latency-bound at 3.2 TB/s with 1-deep prefetch.
// Fully unrolled k-loop keeps all buffer indexing compile-time (no scratch).
__global__ __launch_bounds__(256, 2) void gemm_mfma_kernel(
        const unsigned short* __restrict__ encB,  // [64,256] bf16
        const float* __restrict__ W,              // [256, 262144]
        const float* __restrict__ bias,           // [262144]
        __half* __restrict__ vox) {               // [64, 262144] fp16
    int wave = threadIdx.x >> 6;
    int lane = threadIdx.x & 63;
    int l15 = lane & 15, l4 = lane >> 4;
    int n4 = blockIdx.x * 256 + wave * 64 + 4 * l15;  // cols n4..n4+3

    f32x4 acc[4][4];   // [tile][mt]
#pragma unroll
    for (int t = 0; t < 4; ++t)
#pragma unroll
        for (int mt = 0; mt < 4; ++mt) acc[t][mt] = (f32x4){0.f, 0.f, 0.f, 0.f};

    const unsigned short* ap = encB + l15 * LAT + l4 * 8;
    const float* wp = W + (size_t)(l4 * 8) * VOX + n4;

    float4 w0[8], w1[8], w2[8];

    auto loadbuf = [&](float4* buf, int kb) {
        const float* q = wp + (size_t)kb * VOX;
#pragma unroll
        for (int j = 0; j < 8; ++j)
            buf[j] = *(const float4*)(q + (size_t)j * VOX);
    };

    auto consume = [&](const float4* w, int kb) {
        short8 a[4];
#pragma unroll
        for (int mt = 0; mt < 4; ++mt)
            a[mt] = *(const short8*)(ap + mt * 16 * LAT + kb);
        short8 bf[4];
#pragma unroll
        for (int t = 0; t < 4; ++t) {
            unsigned bw[4];
#pragma unroll
            for (int dw = 0; dw < 4; ++dw) {
                unsigned u0 = __float_as_uint(((const float*)&w[2 * dw])[t])     + 0x8000u;
                unsigned u1 = __float_as_uint(((const float*)&w[2 * dw + 1])[t]) + 0x8000u;
                bw[dw] = __builtin_amdgcn_perm(u1, u0, 0x07060302u);  // hi16(u0)|hi16(u1)<<16
            }
            bf[t] = *reinterpret_cast<short8*>(bw);
        }
#pragma unroll
        for (int t = 0; t < 4; ++t)
#pragma unroll
            for (int mt = 0; mt < 4; ++mt)
                acc[t][mt] = __builtin_amdgcn_mfma_f32_16x16x32_bf16(a[mt], bf[t], acc[t][mt], 0, 0, 0);
    };

    // 3-deep pipeline over 8 k-blocks (LAT/32 = 8), static rotation
    loadbuf(w0, 0);
    loadbuf(w1, 32);
    loadbuf(w2, 64);  consume(w0, 0);     // 2 bufs in flight during consume
    loadbuf(w0, 96);  consume(w1, 32);
    loadbuf(w1, 128); consume(w2, 64);
    loadbuf(w2, 160); consume(w0, 96);
    loadbuf(w0, 192); consume(w1, 128);
    loadbuf(w1, 224); consume(w2, 160);
    consume(w0, 192);
    consume(w1, 224);

    float4 bv = *(const float4*)(bias + n4);
#pragma unroll
    for (int mt = 0; mt < 4; ++mt) {
#pragma unroll
        for (int r = 0; r < 4; ++r) {
            int b = mt * 16 + l4 * 4 + r;
            float s[4];
#pragma unroll
            for (int t = 0; t < 4; ++t) {
                float x = acc[t][mt][r] + ((const float*)&bv)[t];
                float v = 1.f / (1.f + __expf(-x));   // sigmoid
                v = v * v; v = v * v; v = v * v;      // ^8
                s[t] = v;
            }
            __half2 h01 = __floats2half2_rn(s[0], s[1]);
            __half2 h23 = __floats2half2_rn(s[2], s[3]);
            uint2 pk;
            pk.x = *reinterpret_cast<unsigned*>(&h01);
            pk.y = *reinterpret_cast<unsigned*>(&h23);
            *reinterpret_cast<uint2*>(vox + (size_t)b * VOX + n4) = pk;
        }
    }
}

// ---------------- kernel 2: 4-wave cooperative LDS-brick resample ----------
// (exact round-10 build, REP instrumentation removed)
__device__ __forceinline__ float zlerp(unsigned e, float fz) {
    __half2 h = *reinterpret_cast<__half2*>(&e);
    float2 f = __half22float2(h);
    return f.x + (f.y - f.x) * fz;
}

__global__ __launch_bounds__(256) void render_lds_kernel(
        const __half* __restrict__ vox,   // [64, 262144] fp16
        const float* __restrict__ Rmat,   // [64,9]
        float* __restrict__ out) {        // [64,1,64,64]
    __shared__ unsigned sV[16 * 16 * 17]; // 17408 B brick, row stride 17
    __shared__ float sT[4][64], sE[4][64];

    int bid  = blockIdx.x;
    int b    = bid & 63;                  // bid%8 == b%8 -> XCD affinity
    int tile = bid >> 6;
    int t    = threadIdx.x;
    int pix  = t & 63, seg = t >> 6;      // seg == wave id
    int i0 = (tile >> 3) * 8, j0 = (tile & 7) * 8;
    int i = i0 + (pix >> 3);
    int j = j0 + (pix & 7);

    const float* Rb = Rmat + b * 9;       // uniform -> scalar loads
    float R0 = Rb[0], R1 = Rb[1], R2 = Rb[2];
    float R3 = Rb[3], R4 = Rb[4], R5 = Rb[5];
    float R6 = Rb[6], R7 = Rb[7], R8 = Rb[8];

    const float c = (DVOX - 1) * 0.5f;    // 31.5
    float di = (float)i - c, dj = (float)j - c;
    float xb = fmaf(R0, di, fmaf(R1, dj, c));
    float yb = fmaf(R3, di, fmaf(R4, dj, c));
    float zb = fmaf(R6, di, fmaf(R7, dj, c));

    float dic = (float)i0 + 3.5f - c;     // tile-center offsets (uniform)
    float djc = (float)j0 + 3.5f - c;
    float hwx = 3.5f * (fabsf(R0) + fabsf(R1) + fabsf(R2)) + 1e-3f;
    float hwy = 3.5f * (fabsf(R3) + fabsf(R4) + fabsf(R5)) + 1e-3f;
    float hwz = 3.5f * (fabsf(R6) + fabsf(R7) + fabsf(R8)) + 1e-3f;

    const unsigned short* V = (const unsigned short*)vox + (size_t)b * VOX;

    // this thread's staging row: x = t>>4, y = t&15
    int rx = t >> 4, ry = t & 15;
    unsigned d[9];
    int xlo_n, ylo_n, zlo_n, s_n;

    auto bbox = [&](int ch) {
        float dkc = (float)(ch * 8) + 3.5f - c;
        float xc = fmaf(R0, dic, fmaf(R1, djc, fmaf(R2, dkc, c)));
        float yc = fmaf(R3, dic, fmaf(R4, djc, fmaf(R5, dkc, c)));
        float zc = fmaf(R6, dic, fmaf(R7, djc, fmaf(R8, dkc, c)));
        xlo_n = (int)floorf(xc - hwx);
        ylo_n = (int)floorf(yc - hwy);
        zlo_n = (int)floorf(zc - hwz);
        s_n   = zlo_n & ~1;
    };
    auto issue = [&]() {
        int gxc = min(max(xlo_n + rx, 0), DVOX - 1);
        int gyc = min(max(ylo_n + ry, 0), DVOX - 1);
        const unsigned* p = (const unsigned*)(V + ((gxc << 12) + (gyc << 6) + s_n));
        uint32x4 q0 = *(const uint32x4*)p;        // global_load_dwordx4 (4B-align ok)
        uint32x4 q1 = *(const uint32x4*)(p + 4);
        unsigned q2 = p[8];
        d[0] = q0[0]; d[1] = q0[1]; d[2] = q0[2]; d[3] = q0[3];
        d[4] = q1[0]; d[5] = q1[1]; d[6] = q1[2]; d[7] = q1[3];
        d[8] = q2;
    };

    bbox(7); issue();
    int xlo = xlo_n, ylo = ylo_n, zlo = zlo_n, s = s_n;

    float img = 0.f;                      // live in wave 0 only
#pragma unroll 1
    for (int ch = 7; ch >= 0; --ch) {     // back-to-front chunks of 8 z
        bool zint = (zlo >= 0) && (zlo + 17 <= DVOX);

        // ---- pack this thread's row into the brick ------------------------
        {
            bool rv = ((unsigned)(xlo + rx) < (unsigned)DVOX) &
                      ((unsigned)(ylo + ry) < (unsigned)DVOX);
            unsigned tt[9];
#pragma unroll
            for (int k = 0; k < 9; ++k) tt[k] = d[k];
            if (!zint) {                  // block-uniform branch
#pragma unroll
                for (int k = 0; k < 9; ++k) {
                    int h0 = s + 2 * k;
                    unsigned m = (((unsigned)h0 < (unsigned)DVOX) ? 0x0000FFFFu : 0u)
                               | (((unsigned)(h0 + 1) < (unsigned)DVOX) ? 0xFFFF0000u : 0u);
                    tt[k] &= m;
                }
            }
            unsigned rvm = rv ? 0xFFFFFFFFu : 0u;
#pragma unroll
            for (int k = 0; k < 9; ++k) tt[k] &= rvm;

            unsigned A[8];
#pragma unroll
            for (int m = 0; m < 8; ++m)
                A[m] = (tt[m] >> 16) | (tt[m + 1] << 16);   // v_alignbit

            unsigned* wrow = sV + t * 17;
            if (zlo & 1) {                // block-uniform
#pragma unroll
                for (int m = 0; m < 8; ++m) {
                    wrow[2 * m]     = A[m];
                    wrow[2 * m + 1] = tt[m + 1];
                }
            } else {
#pragma unroll
                for (int m = 0; m < 8; ++m) {
                    wrow[2 * m]     = tt[m];
                    wrow[2 * m + 1] = A[m];
                }
            }
        }
        __syncthreads();

        // ---- issue NEXT chunk's loads (latency hides under sampling) ------
        if (ch > 0) { bbox(ch - 1); issue(); }

        // ---- sample this wave's 2-z segment, back-to-front ----------------
        float T = 1.f, E = 0.f;
        int k0 = ch * 8;
#pragma unroll
        for (int q = 1; q >= 0; --q) {    // kk = 2*seg+1, then 2*seg
            int kk = 2 * seg + q;
            float dk = (float)(k0 + kk) - c;
            float x = fmaf(R2, dk, xb);
            float y = fmaf(R5, dk, yb);
            float z = fmaf(R8, dk, zb);

            float xf = floorf(x), yf = floorf(y), zf = floorf(z);
            float fx = x - xf, fy = y - yf, fz = z - zf;
            int xi = (int)xf - xlo;       // [0,14]
            int yi = (int)yf - ylo;
            int zi = (int)zf - zlo;
            const unsigned* e = sV + (xi * 272 + yi * 17 + zi);

            float c00 = zlerp(e[0],   fz);   // (x0,y0)
            float c01 = zlerp(e[17],  fz);   // (x0,y1)
            float c10 = zlerp(e[272], fz);   // (x1,y0)
            float c11 = zlerp(e[289], fz);   // (x1,y1)
            float c0 = c00 + (c01 - c00) * fy;
            float c1 = c10 + (c11 - c10) * fy;
            float a  = c0  + (c1  - c0 ) * fx;

            E = E * (1.f - a) + a;
            T *= (1.f - a);
        }
        sT[seg][pix] = T;
        sE[seg][pix] = E;
        __syncthreads();

        // ---- wave 0 folds the 4 segments (back seg 3 first) ---------------
        if (seg == 0) {
            float im = img;
#pragma unroll
            for (int ss = 3; ss >= 0; --ss)
                im = fmaf(sT[ss][pix], im, sE[ss][pix]);
            img = im;
        }
        // next chunk's sT/sE writes are ordered after this fold by the
        // pack-side __syncthreads() of the next iteration.

        xlo = xlo_n; ylo = ylo_n; zlo = zlo_n; s = s_n;
    }

    if (seg == 0)
        out[b * (DVOX * DVOX) + i * DVOX + j] = 2.f * img - 1.f;
}

// ---------------------------------------------------------------------------
extern "C" void kernel_launch(void* const* d_in, const int* in_sizes, int n_in,
                              void* d_out, int out_size, void* d_ws, size_t ws_size,
                              hipStream_t stream) {
    const float* enc    = (const float*)d_in[0];
    const float* W      = (const float*)d_in[1];
    const float* bias   = (const float*)d_in[2];
    const float* angles = (const float*)d_in[3];
    float* out = (float*)d_out;

    char* ws = (char*)d_ws;
    unsigned short* encB = (unsigned short*)ws;           // 32 KB
    float* Rmat          = (float*)(ws + 32768);          // 2.3 KB
    __half* vox          = (__half*)(ws + 65536);         // 32 MiB

    prep_kernel<<<1, 256, 0, stream>>>(enc, angles, encB, Rmat);
    gemm_mfma_kernel<<<VOX / 256, 256, 0, stream>>>(encB, W, bias, vox);
    render_lds_kernel<<<BATCH * 64, 256, 0, stream>>>(vox, Rmat, out);
}